// Round 2
// baseline (5186.351 us; speedup 1.0000x reference)
//
#include <hip/hip_runtime.h>
#include <math.h>

#define B_   2
#define T_   2048
#define V_   32000
#define DM   1024
#define DI_  2048
#define NS   16
#define RR   64
#define LL   4
#define KK   4
#define BT   (B_*T_)

typedef unsigned short u16;
typedef unsigned int   u32;
// guide-verified operand type for __builtin_amdgcn_mfma_f32_16x16x32_bf16 on gfx950
typedef __attribute__((ext_vector_type(8))) short  bfrag;
typedef __attribute__((ext_vector_type(4))) float  f32x4;

__device__ __forceinline__ float siluf(float x){ return x / (1.0f + __expf(-x)); }
__device__ __forceinline__ float softplusf(float x){
    return (x > 20.0f) ? x : log1pf(__expf(x));
}

// ---------------------------------------------------------------- embedding
__global__ __launch_bounds__(256) void embed_kernel(
    const int* __restrict__ ids, const float* __restrict__ W, float* __restrict__ x)
{
    int idx = blockIdx.x * 256 + threadIdx.x;     // over BT*DM
    int d  = idx & (DM - 1);
    int bt = idx >> 10;
    x[idx] = W[(size_t)ids[bt] * DM + d];
}

// ---------------------------------------------------------------- layernorm (row = 1024)
__global__ __launch_bounds__(256) void ln_kernel(
    const float* __restrict__ x, const float* __restrict__ w,
    const float* __restrict__ b, float* __restrict__ o)
{
    int row = blockIdx.x;
    const float4* xr = (const float4*)(x + (size_t)row * DM);
    float4 v = xr[threadIdx.x];
    float s = v.x + v.y + v.z + v.w;
    float q = v.x*v.x + v.y*v.y + v.z*v.z + v.w*v.w;
    #pragma unroll
    for (int off = 32; off > 0; off >>= 1) {
        s += __shfl_down(s, off);
        q += __shfl_down(q, off);
    }
    __shared__ float rs_[4], rq_[4];
    __shared__ float mu_s, inv_s;
    int lane = threadIdx.x & 63, wv = threadIdx.x >> 6;
    if (lane == 0) { rs_[wv] = s; rq_[wv] = q; }
    __syncthreads();
    if (threadIdx.x == 0) {
        float S = rs_[0] + rs_[1] + rs_[2] + rs_[3];
        float Q = rq_[0] + rq_[1] + rq_[2] + rq_[3];
        float mu  = S * (1.0f / DM);
        float var = Q * (1.0f / DM) - mu * mu;
        mu_s = mu; inv_s = rsqrtf(var + 1e-5f);
    }
    __syncthreads();
    float mu = mu_s, inv = inv_s;
    float4 wv4 = ((const float4*)w)[threadIdx.x];
    float4 bv4 = ((const float4*)b)[threadIdx.x];
    float4 r;
    r.x = (v.x - mu) * inv * wv4.x + bv4.x;
    r.y = (v.y - mu) * inv * wv4.y + bv4.y;
    r.z = (v.z - mu) * inv * wv4.z + bv4.z;
    r.w = (v.w - mu) * inv * wv4.w + bv4.w;
    ((float4*)(o + (size_t)row * DM))[threadIdx.x] = r;
}

// ---------------------------------------------------------------- causal dwconv(K=4) + silu
__global__ __launch_bounds__(256) void conv_silu_kernel(
    const float* __restrict__ xz, const float* __restrict__ cw,
    const float* __restrict__ cb, float* __restrict__ xc)
{
    int idx = blockIdx.x * 256 + threadIdx.x;     // over BT*DI_
    int c  = idx & (DI_ - 1);
    int bt = idx >> 11;
    int t  = bt & (T_ - 1);
    const float* base = xz + (size_t)bt * (2 * DI_) + c;
    float w0 = cw[c*KK+0], w1 = cw[c*KK+1], w2 = cw[c*KK+2], w3 = cw[c*KK+3];
    float acc = cb[c];
    if (t >= 3) acc += base[-3 * 2 * DI_] * w0;
    if (t >= 2) acc += base[-2 * 2 * DI_] * w1;
    if (t >= 1) acc += base[-1 * 2 * DI_] * w2;
    acc += base[0] * w3;
    xc[idx] = siluf(acc);
}

// ---------------------------------------------------------------- selective scan
__global__ __launch_bounds__(256) void scan_kernel(
    const float* __restrict__ dt, int dt_stride,
    const float* __restrict__ u,
    const float* __restrict__ proj,
    const float* __restrict__ z, int z_stride,
    const float* __restrict__ A_log, const float* __restrict__ Dp,
    float* __restrict__ y)
{
    int b   = blockIdx.x / (DI_ / 16);
    int di0 = (blockIdx.x % (DI_ / 16)) * 16;
    int tid = threadIdx.x;
    int ci = tid >> 4, n = tid & 15;
    int di = di0 + ci;
    float Av = -__expf(A_log[di * NS + n]);
    float Dv = Dp[di];

    __shared__ float dt_s[16][16], u_s[16][16], Bs[16][16], Cs[16][16], ys[16][16];

    int li = tid >> 4;
    int lc = tid & 15;

    float h = 0.0f;
    for (int t0 = 0; t0 < T_; t0 += 16) {
        size_t bt = (size_t)b * T_ + t0 + li;
        dt_s[li][lc] = dt[bt * dt_stride + di0 + lc];
        u_s[li][lc]  = u[bt * DI_ + di0 + lc];
        Bs[li][lc]   = proj[bt * (RR + 2*NS) + RR + lc];
        Cs[li][lc]   = proj[bt * (RR + 2*NS) + RR + NS + lc];
        __syncthreads();
        #pragma unroll
        for (int i = 0; i < 16; i++) {
            float dtv = dt_s[i][ci];
            float uv  = u_s[i][ci];
            float dA  = __expf(dtv * Av);
            h = dA * h + dtv * uv * Bs[i][n];
            float p = h * Cs[i][n];
            p += __shfl_xor(p, 1, 16);
            p += __shfl_xor(p, 2, 16);
            p += __shfl_xor(p, 4, 16);
            p += __shfl_xor(p, 8, 16);
            if (n == 0) ys[i][ci] = p + uv * Dv;
        }
        __syncthreads();
        float yv = ys[li][lc];
        float zv = z[bt * z_stride + di0 + lc];
        y[bt * DI_ + di0 + lc] = yv * siluf(zv);
    }
}

// ---------------------------------------------------------------- bf16x3 split helpers
__device__ __forceinline__ u32 bf_rne(float f){
    u32 u = __float_as_uint(f);
    return (u + 0x7fffu + ((u >> 16) & 1u)) >> 16;
}

// hi = truncated top-16 bits (error captured exactly by lo); lo = RNE bf16 of remainder
__device__ __forceinline__ void split4(const float4 v, uint2& hh, uint2& ll){
    u32 hx = __float_as_uint(v.x) >> 16;
    u32 hy = __float_as_uint(v.y) >> 16;
    u32 hz = __float_as_uint(v.z) >> 16;
    u32 hw = __float_as_uint(v.w) >> 16;
    hh.x = hx | (hy << 16);
    hh.y = hz | (hw << 16);
    float lx = v.x - __uint_as_float(hx << 16);
    float ly = v.y - __uint_as_float(hy << 16);
    float lz = v.z - __uint_as_float(hz << 16);
    float lw = v.w - __uint_as_float(hw << 16);
    ll.x = bf_rne(lx) | (bf_rne(ly) << 16);
    ll.y = bf_rne(lz) | (bf_rne(lw) << 16);
}

// ---------------------------------------------------------------- bf16x3 MFMA NT GEMM
// C[m,n] = sum_k A[m,k]*B[n,k]  (+bias[n]) (softplus) (+Res[m,n])
// 128x128 tile, BK=32, 256 threads = 4 waves (2x2), 64x64 per wave.
// Split-fp32: acc += Ah*Bh + Al*Bh + Ah*Bl  (3x mfma_f32_16x16x32_bf16)
// EPI bits: 1=bias, 2=softplus, 4=residual.  NG: N-boundary guard (x_proj N=96).
template<int EPI, bool NG>
__global__ __launch_bounds__(256) void gemm_nt_mfma(
    const float* __restrict__ A, int lda,
    const float* __restrict__ Bm, int ldb,
    float* __restrict__ C, int ldc,
    const float* __restrict__ bias,
    const float* __restrict__ Res, int ldres,
    int N, int Kd)
{
    // 4 planes (Ah, Al, Bh, Bl) x 128 rows x 32 bf16, pitch 40 (80 B: 16B-aligned,
    // rows r and r+8 share banks -> exactly 2-way on ds_read_b128, free per m136)
    __shared__ __align__(16) u16 lds[4][128][40];

    const int tid  = threadIdx.x;
    const int m0   = blockIdx.y * 128, n0 = blockIdx.x * 128;
    const int lane = tid & 63, wave = tid >> 6;
    const int wm   = (wave >> 1) * 64, wn = (wave & 1) * 64;
    const int lr   = lane & 15, lc = lane >> 4;   // frag row, k-chunk (also D row-group)

    f32x4 acc[4][4];
    #pragma unroll
    for (int i = 0; i < 4; i++)
        #pragma unroll
        for (int j = 0; j < 4; j++)
            acc[i][j] = (f32x4){0.f, 0.f, 0.f, 0.f};

    const float* Ab = A  + (size_t)m0 * lda;
    const float* Bb = Bm + (size_t)n0 * ldb;

    for (int k0 = 0; k0 < Kd; k0 += 32) {
        // ---- stage: global fp32 -> registers -> split hi/lo (VALU overlaps prior MFMA)
        uint2 ahh[4], alo[4], bhh[4], blo[4];
        #pragma unroll
        for (int i = 0; i < 4; i++) {
            int idx = tid + i * 256;            // 1024 float4 slots = 128 rows x 8
            int r = idx >> 3, c = (idx & 7) << 2;
            float4 av = *(const float4*)(Ab + (size_t)r * lda + k0 + c);
            float4 bv;
            if (!NG || (n0 + r) < N)
                bv = *(const float4*)(Bb + (size_t)r * ldb + k0 + c);
            else
                bv = make_float4(0.f, 0.f, 0.f, 0.f);
            split4(av, ahh[i], alo[i]);
            split4(bv, bhh[i], blo[i]);
        }
        __syncthreads();                        // prior iter's frag reads done
        #pragma unroll
        for (int i = 0; i < 4; i++) {
            int idx = tid + i * 256;
            int r = idx >> 3, c = (idx & 7) << 2;
            *(uint2*)&lds[0][r][c] = ahh[i];
            *(uint2*)&lds[1][r][c] = alo[i];
            *(uint2*)&lds[2][r][c] = bhh[i];
            *(uint2*)&lds[3][r][c] = blo[i];
        }
        __syncthreads();

        // ---- fragments: 8 consecutive k per row = one ds_read_b128
        bfrag afh[4], afl[4], bfh[4], bfl[4];
        #pragma unroll
        for (int i = 0; i < 4; i++) {
            afh[i] = *(const bfrag*)&lds[0][wm + i*16 + lr][lc*8];
            afl[i] = *(const bfrag*)&lds[1][wm + i*16 + lr][lc*8];
            bfh[i] = *(const bfrag*)&lds[2][wn + i*16 + lr][lc*8];
            bfl[i] = *(const bfrag*)&lds[3][wn + i*16 + lr][lc*8];
        }
        #pragma unroll
        for (int i = 0; i < 4; i++)
            #pragma unroll
            for (int j = 0; j < 4; j++) {
                f32x4 a = acc[i][j];
                a = __builtin_amdgcn_mfma_f32_16x16x32_bf16(afh[i], bfh[j], a, 0, 0, 0);
                a = __builtin_amdgcn_mfma_f32_16x16x32_bf16(afl[i], bfh[j], a, 0, 0, 0);
                a = __builtin_amdgcn_mfma_f32_16x16x32_bf16(afh[i], bfl[j], a, 0, 0, 0);
                acc[i][j] = a;
            }
    }

    // ---- epilogue: D[row][col], col = lane&15, row = (lane>>4)*4 + reg  (m89-verified)
    #pragma unroll
    for (int j = 0; j < 4; j++) {
        int n = n0 + wn + j*16 + lr;
        if (NG && n >= N) continue;
        float bs = (EPI & 1) ? bias[n] : 0.f;
        #pragma unroll
        for (int i = 0; i < 4; i++) {
            #pragma unroll
            for (int r = 0; r < 4; r++) {
                int m = m0 + wm + i*16 + lc*4 + r;
                float v = acc[i][j][r];
                if (EPI & 1) v += bs;
                if (EPI & 2) v = softplusf(v);
                if (EPI & 4) v += Res[(size_t)m * ldres + n];
                C[(size_t)m * ldc + n] = v;
            }
        }
    }
}

// ---------------------------------------------------------------- launch
extern "C" void kernel_launch(void* const* d_in, const int* in_sizes, int n_in,
                              void* d_out, int out_size, void* d_ws, size_t ws_size,
                              hipStream_t stream)
{
    const int*   ids    = (const int*)  d_in[0];
    const float* embedW = (const float*)d_in[1];
    const float* out_b  = (const float*)d_in[2];
    const float* ln_w   = (const float*)d_in[3];
    const float* ln_b   = (const float*)d_in[4];
    const float* norm_w = (const float*)d_in[5];
    const float* norm_b = (const float*)d_in[6];
    const float* inW    = (const float*)d_in[7];   // (L, 2DI, Dm)
    const float* convW  = (const float*)d_in[8];   // (L, DI, K)
    const float* convB  = (const float*)d_in[9];   // (L, DI)
    const float* xW     = (const float*)d_in[10];  // (L, 96, DI)
    const float* dtW    = (const float*)d_in[11];  // (L, DI, R)
    const float* dtB    = (const float*)d_in[12];  // (L, DI)
    const float* Alog   = (const float*)d_in[13];  // (L, DI, N)
    const float* Dp     = (const float*)d_in[14];  // (L, DI)
    const float* oW     = (const float*)d_in[15];  // (L, Dm, DI)

    float* x    = (float*)d_ws;                        // (BT, Dm)    16 MB
    float* h    = x    + (size_t)BT * DM;              // (BT, Dm)    16 MB
    float* xz   = h    + (size_t)BT * DM;              // (BT, 2*DI)  64 MB
    float* xc   = xz   + (size_t)BT * 2 * DI_;         // (BT, DI)    32 MB
    float* proj = xc   + (size_t)BT * DI_;             // (BT, 96)   1.5 MB
    float* logits = (float*)d_out;

    embed_kernel<<<BT*DM/256, 256, 0, stream>>>(ids, embedW, x);

    for (int l = 0; l < LL; l++) {
        // h = LN(x)
        ln_kernel<<<BT, 256, 0, stream>>>(x, norm_w + (size_t)l*DM, norm_b + (size_t)l*DM, h);
        // xz = h @ inW^T   (M=4096, N=4096, K=1024)
        gemm_nt_mfma<0, false><<<dim3(4096/128, BT/128), 256, 0, stream>>>(
            h, DM, inW + (size_t)l*2*DI_*DM, DM, xz, 2*DI_,
            nullptr, nullptr, 0, 2*DI_, DM);
        // xc = silu(conv(x_in) + cb)
        conv_silu_kernel<<<BT*DI_/256, 256, 0, stream>>>(
            xz, convW + (size_t)l*DI_*KK, convB + (size_t)l*DI_, xc);
        // proj = xc @ xW^T  (M=4096, N=96, K=2048) — N-guarded tile
        gemm_nt_mfma<0, true><<<dim3(1, BT/128), 256, 0, stream>>>(
            xc, DI_, xW + (size_t)l*(RR+2*NS)*DI_, DI_, proj, RR+2*NS,
            nullptr, nullptr, 0, RR+2*NS, DI_);
        // dt = softplus(proj[:, :R] @ dtW^T + dtB)  -> x_in slots of xz
        gemm_nt_mfma<3, false><<<dim3(DI_/128, BT/128), 256, 0, stream>>>(
            proj, RR+2*NS, dtW + (size_t)l*DI_*RR, RR, xz, 2*DI_,
            dtB + (size_t)l*DI_, nullptr, 0, DI_, RR);
        // selective scan: y (in-place over xc) = (scan + u*D) * silu(z)
        scan_kernel<<<B_*(DI_/16), 256, 0, stream>>>(
            xz, 2*DI_, xc, proj, xz + DI_, 2*DI_,
            Alog + (size_t)l*DI_*NS, Dp + (size_t)l*DI_, xc);
        // x = x + y @ oW^T  (M=4096, N=1024, K=2048)
        gemm_nt_mfma<4, false><<<dim3(DM/128, BT/128), 256, 0, stream>>>(
            xc, DI_, oW + (size_t)l*DM*DI_, DI_, x, DM,
            nullptr, x, DM, DM, DI_);
    }

    // final LN + logits
    ln_kernel<<<BT, 256, 0, stream>>>(x, ln_w, ln_b, h);
    // logits = h @ embedW^T + out_b  (M=4096, N=32000, K=1024)
    gemm_nt_mfma<1, false><<<dim3(V_/128, BT/128), 256, 0, stream>>>(
        h, DM, embedW, DM, logits, V_,
        out_b, nullptr, 0, V_, DM);
}

// Round 3
// 3422.820 us; speedup vs baseline: 1.5152x; 1.5152x over previous
//
#include <hip/hip_runtime.h>
#include <math.h>

#define B_   2
#define T_   2048
#define V_   32000
#define DM   1024
#define DI_  2048
#define NS   16
#define RR   64
#define LL   4
#define KK   4
#define BT   (B_*T_)

typedef unsigned short u16;
typedef unsigned int   u32;
typedef __attribute__((ext_vector_type(8))) short  bfrag;
typedef __attribute__((ext_vector_type(4))) float  f32x4;

__device__ __forceinline__ float siluf(float x){ return x / (1.0f + __expf(-x)); }
__device__ __forceinline__ float softplusf(float x){
    return (x > 20.0f) ? x : log1pf(__expf(x));
}

// ---------------------------------------------------------------- split helpers
__device__ __forceinline__ u32 bf_rne(float f){
    u32 u = __float_as_uint(f);
    return (u + 0x7fffu + ((u >> 16) & 1u)) >> 16;
}
__device__ __forceinline__ void split4(const float4 v, uint2& hh, uint2& ll){
    u32 hx = __float_as_uint(v.x) >> 16;
    u32 hy = __float_as_uint(v.y) >> 16;
    u32 hz = __float_as_uint(v.z) >> 16;
    u32 hw = __float_as_uint(v.w) >> 16;
    hh.x = hx | (hy << 16);
    hh.y = hz | (hw << 16);
    float lx = v.x - __uint_as_float(hx << 16);
    float ly = v.y - __uint_as_float(hy << 16);
    float lz = v.z - __uint_as_float(hz << 16);
    float lw = v.w - __uint_as_float(hw << 16);
    ll.x = bf_rne(lx) | (bf_rne(ly) << 16);
    ll.y = bf_rne(lz) | (bf_rne(lw) << 16);
}
__device__ __forceinline__ void split1(float v, u16& h, u16& l){
    u32 hv = __float_as_uint(v) >> 16;
    h = (u16)hv;
    l = (u16)bf_rne(v - __uint_as_float(hv << 16));
}

// async global->LDS, 16B per lane; dest = wave-uniform base + lane*16
__device__ __forceinline__ void gload16(const void* g, void* l){
    __builtin_amdgcn_global_load_lds(
        (const __attribute__((address_space(1))) unsigned int*)g,
        (__attribute__((address_space(3))) unsigned int*)l, 16, 0, 0);
}

// ---------------------------------------------------------------- embedding
__global__ __launch_bounds__(256) void embed_kernel(
    const int* __restrict__ ids, const float* __restrict__ W, float* __restrict__ x)
{
    int idx = blockIdx.x * 256 + threadIdx.x;
    int d  = idx & (DM - 1);
    int bt = idx >> 10;
    x[idx] = W[(size_t)ids[bt] * DM + d];
}

// ---------------------------------------------------------------- layernorm (row = 1024)
// optional outputs: f32 row, and/or bf16 hi/lo planes
__global__ __launch_bounds__(256) void ln_kernel(
    const float* __restrict__ x, const float* __restrict__ w,
    const float* __restrict__ b, float* __restrict__ o,
    u16* __restrict__ oh, u16* __restrict__ ol)
{
    int row = blockIdx.x;
    const float4* xr = (const float4*)(x + (size_t)row * DM);
    float4 v = xr[threadIdx.x];
    float s = v.x + v.y + v.z + v.w;
    float q = v.x*v.x + v.y*v.y + v.z*v.z + v.w*v.w;
    #pragma unroll
    for (int off = 32; off > 0; off >>= 1) {
        s += __shfl_down(s, off);
        q += __shfl_down(q, off);
    }
    __shared__ float rs_[4], rq_[4];
    __shared__ float mu_s, inv_s;
    int lane = threadIdx.x & 63, wv = threadIdx.x >> 6;
    if (lane == 0) { rs_[wv] = s; rq_[wv] = q; }
    __syncthreads();
    if (threadIdx.x == 0) {
        float S = rs_[0] + rs_[1] + rs_[2] + rs_[3];
        float Q = rq_[0] + rq_[1] + rq_[2] + rq_[3];
        float mu  = S * (1.0f / DM);
        float var = Q * (1.0f / DM) - mu * mu;
        mu_s = mu; inv_s = rsqrtf(var + 1e-5f);
    }
    __syncthreads();
    float mu = mu_s, inv = inv_s;
    float4 wv4 = ((const float4*)w)[threadIdx.x];
    float4 bv4 = ((const float4*)b)[threadIdx.x];
    float4 r;
    r.x = (v.x - mu) * inv * wv4.x + bv4.x;
    r.y = (v.y - mu) * inv * wv4.y + bv4.y;
    r.z = (v.z - mu) * inv * wv4.z + bv4.z;
    r.w = (v.w - mu) * inv * wv4.w + bv4.w;
    if (o) ((float4*)(o + (size_t)row * DM))[threadIdx.x] = r;
    if (oh) {
        uint2 hh, ll; split4(r, hh, ll);
        ((uint2*)(oh + (size_t)row * DM))[threadIdx.x] = hh;
        ((uint2*)(ol + (size_t)row * DM))[threadIdx.x] = ll;
    }
}

// ---------------------------------------------------------------- causal dwconv(K=4) + silu
__global__ __launch_bounds__(256) void conv_silu_kernel(
    const float* __restrict__ xz, const float* __restrict__ cw,
    const float* __restrict__ cb, float* __restrict__ xc,
    u16* __restrict__ xh, u16* __restrict__ xl)
{
    int idx = blockIdx.x * 256 + threadIdx.x;
    int c  = idx & (DI_ - 1);
    int bt = idx >> 11;
    int t  = bt & (T_ - 1);
    const float* base = xz + (size_t)bt * (2 * DI_) + c;
    float w0 = cw[c*KK+0], w1 = cw[c*KK+1], w2 = cw[c*KK+2], w3 = cw[c*KK+3];
    float acc = cb[c];
    if (t >= 3) acc += base[-3 * 2 * DI_] * w0;
    if (t >= 2) acc += base[-2 * 2 * DI_] * w1;
    if (t >= 1) acc += base[-1 * 2 * DI_] * w2;
    acc += base[0] * w3;
    float v = siluf(acc);
    xc[idx] = v;
    if (xh) { u16 h, l; split1(v, h, l); xh[idx] = h; xl[idx] = l; }
}

// ---------------------------------------------------------------- selective scan (2-phase, shfl-free)
// block 256 = 16 channels x 16 states; per 16-t chunk:
//  phase1: thread (ci,n): serial recurrence, products to ps[i][ci][n] (D-term folded at n==0)
//  phase2: thread (t=li,ch=lc): sum 16 states from LDS, apply silu(z), emit y (f32 and/or planes)
__global__ __launch_bounds__(256) void scan_kernel(
    const float* __restrict__ dt, int dt_stride,
    const float* __restrict__ u,
    const float* __restrict__ proj,
    const float* __restrict__ z, int z_stride,
    const float* __restrict__ A_log, const float* __restrict__ Dp,
    float* __restrict__ yf, u16* __restrict__ yh, u16* __restrict__ yl)
{
    int b   = blockIdx.x / (DI_ / 16);
    int di0 = (blockIdx.x % (DI_ / 16)) * 16;
    int tid = threadIdx.x;
    int ci = tid >> 4, n = tid & 15;      // phase-1 role
    int li = tid >> 4, lc = tid & 15;     // load / phase-2 role
    int di = di0 + ci;
    float Av = -__expf(A_log[di * NS + n]);
    float Dv = Dp[di];

    __shared__ float dt_s[16][16], u_s[16][16], Bs[16][16], Cs[16][16];
    __shared__ float ps[16][16][17];      // padded: phase2 reads 2-way conflict-free

    // prefetch chunk 0
    size_t bt0 = (size_t)b * T_ + li;
    float r_dt = dt[bt0 * dt_stride + di0 + lc];
    float r_u  = u[bt0 * DI_ + di0 + lc];
    float r_B  = proj[bt0 * (RR + 2*NS) + RR + lc];
    float r_C  = proj[bt0 * (RR + 2*NS) + RR + NS + lc];
    float r_z  = z[bt0 * z_stride + di0 + lc];

    float h = 0.0f;
    for (int t0 = 0; t0 < T_; t0 += 16) {
        dt_s[li][lc] = r_dt; u_s[li][lc] = r_u; Bs[li][lc] = r_B; Cs[li][lc] = r_C;
        float cz = r_z;
        if (t0 + 16 < T_) {               // prefetch next chunk (in flight during compute)
            size_t bt2 = (size_t)b * T_ + t0 + 16 + li;
            r_dt = dt[bt2 * dt_stride + di0 + lc];
            r_u  = u[bt2 * DI_ + di0 + lc];
            r_B  = proj[bt2 * (RR + 2*NS) + RR + lc];
            r_C  = proj[bt2 * (RR + 2*NS) + RR + NS + lc];
            r_z  = z[bt2 * z_stride + di0 + lc];
        }
        __syncthreads();
        #pragma unroll
        for (int i = 0; i < 16; i++) {
            float dtv = dt_s[i][ci];
            float uv  = u_s[i][ci];
            float dA  = __expf(dtv * Av);           // indep of h: compiler hoists
            h = dA * h + dtv * uv * Bs[i][n];
            float p = h * Cs[i][n];
            if (n == 0) p += uv * Dv;               // fold D-term
            ps[i][ci][n] = p;
        }
        __syncthreads();
        float s = 0.0f;
        #pragma unroll
        for (int k = 0; k < 16; k++) s += ps[li][lc][k];
        size_t bty = (size_t)b * T_ + t0 + li;
        float yv = s * siluf(cz);
        size_t oidx = bty * DI_ + di0 + lc;
        if (yf) yf[oidx] = yv;
        if (yh) { u16 hv, lv; split1(yv, hv, lv); yh[oidx] = hv; yl[oidx] = lv; }
    }
}

// ---------------------------------------------------------------- weight conversion
__global__ __launch_bounds__(256) void split_kernel(
    const float* __restrict__ src, u16* __restrict__ hi, u16* __restrict__ lo, int n4)
{
    int i = blockIdx.x * 256 + threadIdx.x;
    int stride = gridDim.x * 256;
    for (; i < n4; i += stride) {
        float4 v = ((const float4*)src)[i];
        uint2 hh, ll; split4(v, hh, ll);
        ((uint2*)hi)[i] = hh; ((uint2*)lo)[i] = ll;
    }
}

// xW (L,96,DI) -> padded (L,128,DI) planes, zero rows 96..127
__global__ __launch_bounds__(256) void split_xw_kernel(
    const float* __restrict__ src, u16* __restrict__ hi, u16* __restrict__ lo)
{
    int idx = blockIdx.x * 256 + threadIdx.x;    // L*128*DI = 1048576
    int l = idx >> 18;
    int rem = idx & 262143;
    int r = rem >> 11, cc = rem & 2047;
    float v = (r < 96) ? src[((size_t)l * 96 + r) * DI_ + cc] : 0.0f;
    u16 h, lo_; split1(v, h, lo_);
    hi[idx] = h; lo[idx] = lo_;
}

// sum 8 split-K partials -> proj f32 + planes
__global__ __launch_bounds__(256) void reduce_xproj(
    const float* __restrict__ part, float* __restrict__ proj,
    u16* __restrict__ ph, u16* __restrict__ pl)
{
    int idx = blockIdx.x * 256 + threadIdx.x;    // BT*96
    float s = 0.0f;
    #pragma unroll
    for (int k = 0; k < 8; k++) s += part[(size_t)k * BT * 96 + idx];
    proj[idx] = s;
    u16 h, l; split1(s, h, l); ph[idx] = h; pl[idx] = l;
}

// ---------------------------------------------------------------- bf16x3 MFMA NT GEMM (pre-split planes)
// C[m,n] = sum_k A[m,k]*B[n,k]; 128x128 tile, BK=32, 4 waves (2x2), 64x64/wave.
// Staging: wave w stages plane w via global_load_lds (16B), source pre-swizzled
// chunk ^ ((row>>1)&3) so swizzled ds_read_b128 frag reads are conflict-free.
// EPI bits: 1=bias, 2=softplus, 4=residual.  SPLITK: blockIdx.x = k-slice (of 8), n0=0.
template<int EPI, bool SPLITK>
__global__ __launch_bounds__(256) void gemm_bf3(
    const u16* __restrict__ Ah, const u16* __restrict__ Al, int lda,
    const u16* __restrict__ Bh, const u16* __restrict__ Bl, int ldb,
    float* __restrict__ C, int ldc,
    const float* __restrict__ bias,
    const float* __restrict__ Res, int ldres,
    int N, int Kd)
{
    __shared__ u16 lds[4][128][32];      // Ah, Al, Bh, Bl planes; linear (gload dest)

    const int tid  = threadIdx.x;
    const int lane = tid & 63, wave = tid >> 6;
    const int m0 = blockIdx.y * 128;
    int n0, kbeg, kend;
    float* Cb = C;
    if (SPLITK) {
        n0 = 0;
        int KS = Kd >> 3;
        kbeg = blockIdx.x * KS; kend = kbeg + KS;
        Cb = C + (size_t)blockIdx.x * BT * 96;
    } else {
        n0 = blockIdx.x * 128; kbeg = 0; kend = Kd;
    }

    const int lr = lane & 15, lc = lane >> 4;
    const int rsw = (lr >> 1) & 3;                 // read-side swizzle
    const int wm = (wave >> 1) * 64, wn = (wave & 1) * 64;

    f32x4 acc[4][4];
    #pragma unroll
    for (int i = 0; i < 4; i++)
        #pragma unroll
        for (int j = 0; j < 4; j++)
            acc[i][j] = (f32x4){0.f, 0.f, 0.f, 0.f};

    // per-wave staging source: plane = wave; source chunk pre-swizzled
    const u16* mat = (wave == 0) ? Ah : (wave == 1) ? Al : (wave == 2) ? Bh : Bl;
    const size_t ldby = ((wave < 2) ? (size_t)lda : (size_t)ldb) * 2;
    const int r0 = (wave < 2) ? m0 : n0;
    const char* gsrc = (const char*)mat + (size_t)(r0 + (lane >> 2)) * ldby
                     + ((((lane & 3) ^ ((lane >> 3) & 3))) << 4);

    for (int k0 = kbeg; k0 < kend; k0 += 32) {
        const char* g = gsrc + (size_t)k0 * 2;
        #pragma unroll
        for (int c = 0; c < 8; c++)
            gload16(g + (size_t)c * 16 * ldby, (void*)&lds[wave][c * 16][0]);
        __syncthreads();                           // vmcnt(0) drain + barrier

        const int cs = (lc ^ rsw) * 8;
        bfrag afh[4], bfh[4];
        #pragma unroll
        for (int i = 0; i < 4; i++) {
            afh[i] = *(const bfrag*)&lds[0][wm + i*16 + lr][cs];
            bfh[i] = *(const bfrag*)&lds[2][wn + i*16 + lr][cs];
        }
        #pragma unroll
        for (int i = 0; i < 4; i++)
            #pragma unroll
            for (int j = 0; j < 4; j++)
                acc[i][j] = __builtin_amdgcn_mfma_f32_16x16x32_bf16(afh[i], bfh[j], acc[i][j], 0, 0, 0);
        bfrag afl[4];
        #pragma unroll
        for (int i = 0; i < 4; i++)
            afl[i] = *(const bfrag*)&lds[1][wm + i*16 + lr][cs];
        #pragma unroll
        for (int i = 0; i < 4; i++)
            #pragma unroll
            for (int j = 0; j < 4; j++)
                acc[i][j] = __builtin_amdgcn_mfma_f32_16x16x32_bf16(afl[i], bfh[j], acc[i][j], 0, 0, 0);
        bfrag bfl[4];
        #pragma unroll
        for (int i = 0; i < 4; i++)
            bfl[i] = *(const bfrag*)&lds[3][wn + i*16 + lr][cs];
        #pragma unroll
        for (int i = 0; i < 4; i++)
            #pragma unroll
            for (int j = 0; j < 4; j++)
                acc[i][j] = __builtin_amdgcn_mfma_f32_16x16x32_bf16(afh[i], bfl[j], acc[i][j], 0, 0, 0);
        __syncthreads();                           // frag reads done before next stage
    }

    // epilogue: D col = lane&15, row = (lane>>4)*4 + reg (m89-verified, round-2-passed)
    #pragma unroll
    for (int j = 0; j < 4; j++) {
        int nn = n0 + wn + j*16 + lr;
        if (nn < N) {
            float bs = (EPI & 1) ? bias[nn] : 0.f;
            #pragma unroll
            for (int i = 0; i < 4; i++) {
                #pragma unroll
                for (int r = 0; r < 4; r++) {
                    int m = m0 + wm + i*16 + lc*4 + r;
                    float v = acc[i][j][r];
                    if (EPI & 1) v += bs;
                    if (EPI & 2) v = softplusf(v);
                    if (EPI & 4) v += Res[(size_t)m * ldres + nn];
                    Cb[(size_t)m * ldc + nn] = v;
                }
            }
        }
    }
}

// ---------------------------------------------------------------- round-2 GEMM (ws-size fallback)
template<int EPI, bool NG>
__global__ __launch_bounds__(256) void gemm_nt_mfma(
    const float* __restrict__ A, int lda,
    const float* __restrict__ Bm, int ldb,
    float* __restrict__ C, int ldc,
    const float* __restrict__ bias,
    const float* __restrict__ Res, int ldres,
    int N, int Kd)
{
    __shared__ __align__(16) u16 lds[4][128][40];
    const int tid  = threadIdx.x;
    const int m0   = blockIdx.y * 128, n0 = blockIdx.x * 128;
    const int lane = tid & 63, wave = tid >> 6;
    const int wm   = (wave >> 1) * 64, wn = (wave & 1) * 64;
    const int lr   = lane & 15, lc = lane >> 4;
    f32x4 acc[4][4];
    #pragma unroll
    for (int i = 0; i < 4; i++)
        #pragma unroll
        for (int j = 0; j < 4; j++)
            acc[i][j] = (f32x4){0.f, 0.f, 0.f, 0.f};
    const float* Ab = A  + (size_t)m0 * lda;
    const float* Bb = Bm + (size_t)n0 * ldb;
    for (int k0 = 0; k0 < Kd; k0 += 32) {
        uint2 ahh[4], alo[4], bhh[4], blo[4];
        #pragma unroll
        for (int i = 0; i < 4; i++) {
            int idx = tid + i * 256;
            int r = idx >> 3, c = (idx & 7) << 2;
            float4 av = *(const float4*)(Ab + (size_t)r * lda + k0 + c);
            float4 bv;
            if (!NG || (n0 + r) < N)
                bv = *(const float4*)(Bb + (size_t)r * ldb + k0 + c);
            else
                bv = make_float4(0.f,0.f,0.f,0.f);
            split4(av, ahh[i], alo[i]);
            split4(bv, bhh[i], blo[i]);
        }
        __syncthreads();
        #pragma unroll
        for (int i = 0; i < 4; i++) {
            int idx = tid + i * 256;
            int r = idx >> 3, c = (idx & 7) << 2;
            *(uint2*)&lds[0][r][c] = ahh[i];
            *(uint2*)&lds[1][r][c] = alo[i];
            *(uint2*)&lds[2][r][c] = bhh[i];
            *(uint2*)&lds[3][r][c] = blo[i];
        }
        __syncthreads();
        bfrag afh[4], afl[4], bfh[4], bfl[4];
        #pragma unroll
        for (int i = 0; i < 4; i++) {
            afh[i] = *(const bfrag*)&lds[0][wm + i*16 + lr][lc*8];
            afl[i] = *(const bfrag*)&lds[1][wm + i*16 + lr][lc*8];
            bfh[i] = *(const bfrag*)&lds[2][wn + i*16 + lr][lc*8];
            bfl[i] = *(const bfrag*)&lds[3][wn + i*16 + lr][lc*8];
        }
        #pragma unroll
        for (int i = 0; i < 4; i++)
            #pragma unroll
            for (int j = 0; j < 4; j++) {
                f32x4 a = acc[i][j];
                a = __builtin_amdgcn_mfma_f32_16x16x32_bf16(afh[i], bfh[j], a, 0, 0, 0);
                a = __builtin_amdgcn_mfma_f32_16x16x32_bf16(afl[i], bfh[j], a, 0, 0, 0);
                a = __builtin_amdgcn_mfma_f32_16x16x32_bf16(afh[i], bfl[j], a, 0, 0, 0);
                acc[i][j] = a;
            }
    }
    #pragma unroll
    for (int j = 0; j < 4; j++) {
        int n = n0 + wn + j*16 + lr;
        if (NG && n >= N) continue;
        float bs = (EPI & 1) ? bias[n] : 0.f;
        #pragma unroll
        for (int i = 0; i < 4; i++) {
            #pragma unroll
            for (int r = 0; r < 4; r++) {
                int m = m0 + wm + i*16 + lc*4 + r;
                float v = acc[i][j][r];
                if (EPI & 1) v += bs;
                if (EPI & 2) v = softplusf(v);
                if (EPI & 4) v += Res[(size_t)m * ldres + n];
                C[(size_t)m * ldc + n] = v;
            }
        }
    }
}

// ---------------------------------------------------------------- launch
extern "C" void kernel_launch(void* const* d_in, const int* in_sizes, int n_in,
                              void* d_out, int out_size, void* d_ws, size_t ws_size,
                              hipStream_t stream)
{
    const int*   ids    = (const int*)  d_in[0];
    const float* embedW = (const float*)d_in[1];
    const float* out_b  = (const float*)d_in[2];
    const float* ln_w   = (const float*)d_in[3];
    const float* ln_b   = (const float*)d_in[4];
    const float* norm_w = (const float*)d_in[5];
    const float* norm_b = (const float*)d_in[6];
    const float* inW    = (const float*)d_in[7];
    const float* convW  = (const float*)d_in[8];
    const float* convB  = (const float*)d_in[9];
    const float* xW     = (const float*)d_in[10];
    const float* dtW    = (const float*)d_in[11];
    const float* dtB    = (const float*)d_in[12];
    const float* Alog   = (const float*)d_in[13];
    const float* Dp     = (const float*)d_in[14];
    const float* oW     = (const float*)d_in[15];
    float* logits = (float*)d_out;

    // ---- workspace layout (new path)
    const size_t fX  = (size_t)BT * DM;
    const size_t fXZ = (size_t)BT * 2 * DI_;
    const size_t fXC = (size_t)BT * DI_;
    const size_t fPJ = (size_t)BT * 96;
    float* x    = (float*)d_ws;
    float* xz   = x    + fX;
    float* xc   = xz   + fXZ;
    float* proj = xc   + fXC;
    float* part = proj + fPJ;
    u16* p16 = (u16*)(part + 8 * fPJ);
    u16* hh  = p16; p16 += fX;   u16* hl  = p16; p16 += fX;
    u16* xch = p16; p16 += fXC;  u16* xcl = p16; p16 += fXC;
    u16* pjh = p16; p16 += fPJ;  u16* pjl = p16; p16 += fPJ;
    const size_t winW = (size_t)LL * 2 * DI_ * DM;
    u16* inWh = p16; p16 += winW; u16* inWl = p16; p16 += winW;
    const size_t wxW = (size_t)LL * 128 * DI_;
    u16* xWh = p16; p16 += wxW;  u16* xWl = p16; p16 += wxW;
    const size_t wdtW = (size_t)LL * DI_ * RR;
    u16* dtWh = p16; p16 += wdtW; u16* dtWl = p16; p16 += wdtW;
    const size_t woW = (size_t)LL * DM * DI_;
    u16* oWh = p16; p16 += woW;  u16* oWl = p16; p16 += woW;
    const size_t weW = (size_t)V_ * DM;
    u16* eWh = p16; p16 += weW;  u16* eWl = p16; p16 += weW;
    const size_t NEED = (size_t)((char*)p16 - (char*)d_ws);

    if (ws_size < NEED) {
        // ---------------- fallback: round-2 pipeline (verified 5186 us)
        float* fx    = (float*)d_ws;
        float* fh    = fx + fX;
        float* fxz   = fh + fX;
        float* fxc   = fxz + fXZ;
        float* fproj = fxc + fXC;
        embed_kernel<<<BT*DM/256, 256, 0, stream>>>(ids, embedW, fx);
        for (int l = 0; l < LL; l++) {
            ln_kernel<<<BT, 256, 0, stream>>>(fx, norm_w + (size_t)l*DM, norm_b + (size_t)l*DM, fh, nullptr, nullptr);
            gemm_nt_mfma<0, false><<<dim3(32, 32), 256, 0, stream>>>(
                fh, DM, inW + (size_t)l*2*DI_*DM, DM, fxz, 2*DI_, nullptr, nullptr, 0, 2*DI_, DM);
            conv_silu_kernel<<<BT*DI_/256, 256, 0, stream>>>(
                fxz, convW + (size_t)l*DI_*KK, convB + (size_t)l*DI_, fxc, nullptr, nullptr);
            gemm_nt_mfma<0, true><<<dim3(1, 32), 256, 0, stream>>>(
                fxc, DI_, xW + (size_t)l*(RR+2*NS)*DI_, DI_, fproj, RR+2*NS, nullptr, nullptr, 0, RR+2*NS, DI_);
            gemm_nt_mfma<3, false><<<dim3(16, 32), 256, 0, stream>>>(
                fproj, RR+2*NS, dtW + (size_t)l*DI_*RR, RR, fxz, 2*DI_, dtB + (size_t)l*DI_, nullptr, 0, DI_, RR);
            scan_kernel<<<B_*(DI_/16), 256, 0, stream>>>(
                fxz, 2*DI_, fxc, fproj, fxz + DI_, 2*DI_,
                Alog + (size_t)l*DI_*NS, Dp + (size_t)l*DI_, fxc, nullptr, nullptr);
            gemm_nt_mfma<4, false><<<dim3(8, 32), 256, 0, stream>>>(
                fxc, DI_, oW + (size_t)l*DM*DI_, DI_, fx, DM, nullptr, fx, DM, DM, DI_);
        }
        ln_kernel<<<BT, 256, 0, stream>>>(fx, ln_w, ln_b, fh, nullptr, nullptr);
        gemm_nt_mfma<1, false><<<dim3(V_/128, 32), 256, 0, stream>>>(
            fh, DM, embedW, DM, logits, V_, out_b, nullptr, 0, V_, DM);
        return;
    }

    // ---------------- new path: pre-split planes + gload_lds GEMM
    split_kernel<<<4096, 256, 0, stream>>>(inW, inWh, inWl, (int)(winW / 4));
    split_kernel<<<2048, 256, 0, stream>>>(dtW, dtWh, dtWl, (int)(wdtW / 4));
    split_kernel<<<4096, 256, 0, stream>>>(oW, oWh, oWl, (int)(woW / 4));
    split_kernel<<<8192, 256, 0, stream>>>(embedW, eWh, eWl, (int)(weW / 4));
    split_xw_kernel<<<4096, 256, 0, stream>>>(xW, xWh, xWl);

    embed_kernel<<<BT*DM/256, 256, 0, stream>>>(ids, embedW, x);

    for (int l = 0; l < LL; l++) {
        // h planes = LN(x)
        ln_kernel<<<BT, 256, 0, stream>>>(x, norm_w + (size_t)l*DM, norm_b + (size_t)l*DM,
                                          nullptr, hh, hl);
        // xz = h @ inW^T   (M=4096, N=4096, K=1024)
        gemm_bf3<0, false><<<dim3(32, 32), 256, 0, stream>>>(
            hh, hl, DM, inWh + l*2*DI_*DM, inWl + l*2*DI_*DM, DM,
            xz, 2*DI_, nullptr, nullptr, 0, 2*DI_, DM);
        // xc (+planes) = silu(conv(x_in) + cb)
        conv_silu_kernel<<<BT*DI_/256, 256, 0, stream>>>(
            xz, convW + (size_t)l*DI_*KK, convB + (size_t)l*DI_, xc, xch, xcl);
        // x_proj split-K x8: partial[s] = xc @ xW^T slice  (N=96 padded to 128)
        gemm_bf3<0, true><<<dim3(8, 32), 256, 0, stream>>>(
            xch, xcl, DI_, xWh + l*128*DI_, xWl + l*128*DI_, DI_,
            part, 96, nullptr, nullptr, 0, 96, DI_);
        reduce_xproj<<<BT*96/256, 256, 0, stream>>>(part, proj, pjh, pjl);
        // dt = softplus(proj[:, :R] @ dtW^T + dtB) -> x_in slots of xz
        gemm_bf3<3, false><<<dim3(16, 32), 256, 0, stream>>>(
            pjh, pjl, 96, dtWh + l*DI_*RR, dtWl + l*DI_*RR, RR,
            xz, 2*DI_, dtB + (size_t)l*DI_, nullptr, 0, DI_, RR);
        // scan: y planes (into xch/xcl, conv planes dead) = (scan + u*D) * silu(z)
        scan_kernel<<<B_*(DI_/16), 256, 0, stream>>>(
            xz, 2*DI_, xc, proj, xz + DI_, 2*DI_,
            Alog + (size_t)l*DI_*NS, Dp + (size_t)l*DI_, nullptr, xch, xcl);
        // x += y @ oW^T
        gemm_bf3<4, false><<<dim3(8, 32), 256, 0, stream>>>(
            xch, xcl, DI_, oWh + l*DM*DI_, oWl + l*DM*DI_, DI_,
            x, DM, nullptr, x, DM, DM, DI_);
    }

    ln_kernel<<<BT, 256, 0, stream>>>(x, ln_w, ln_b, nullptr, hh, hl);
    // logits = h @ embedW^T + out_b  (M=4096, N=32000, K=1024)
    gemm_bf3<1, false><<<dim3(V_/128, 32), 256, 0, stream>>>(
        hh, hl, DM, eWh, eWl, DM, logits, V_, out_b, nullptr, 0, V_, DM);
}

// Round 4
// 3102.761 us; speedup vs baseline: 1.6715x; 1.1032x over previous
//
#include <hip/hip_runtime.h>
#include <math.h>

#define B_   2
#define T_   2048
#define V_   32000
#define DM   1024
#define DI_  2048
#define NS   16
#define RR   64
#define LL   4
#define KK   4
#define BT   (B_*T_)

typedef unsigned short u16;
typedef unsigned int   u32;
typedef __attribute__((ext_vector_type(8))) short  bfrag;
typedef __attribute__((ext_vector_type(4))) float  f32x4;

__device__ __forceinline__ float siluf(float x){ return x / (1.0f + __expf(-x)); }
__device__ __forceinline__ float softplusf(float x){
    return (x > 20.0f) ? x : log1pf(__expf(x));
}

// ---------------------------------------------------------------- split helpers
__device__ __forceinline__ u32 bf_rne(float f){
    u32 u = __float_as_uint(f);
    return (u + 0x7fffu + ((u >> 16) & 1u)) >> 16;
}
__device__ __forceinline__ void split4(const float4 v, uint2& hh, uint2& ll){
    u32 hx = __float_as_uint(v.x) >> 16;
    u32 hy = __float_as_uint(v.y) >> 16;
    u32 hz = __float_as_uint(v.z) >> 16;
    u32 hw = __float_as_uint(v.w) >> 16;
    hh.x = hx | (hy << 16);
    hh.y = hz | (hw << 16);
    float lx = v.x - __uint_as_float(hx << 16);
    float ly = v.y - __uint_as_float(hy << 16);
    float lz = v.z - __uint_as_float(hz << 16);
    float lw = v.w - __uint_as_float(hw << 16);
    ll.x = bf_rne(lx) | (bf_rne(ly) << 16);
    ll.y = bf_rne(lz) | (bf_rne(lw) << 16);
}
__device__ __forceinline__ void split1(float v, u16& h, u16& l){
    u32 hv = __float_as_uint(v) >> 16;
    h = (u16)hv;
    l = (u16)bf_rne(v - __uint_as_float(hv << 16));
}

// async global->LDS, 16B per lane; dest = wave-uniform base + lane*16
__device__ __forceinline__ void gload16(const void* g, void* l){
    __builtin_amdgcn_global_load_lds(
        (const __attribute__((address_space(1))) unsigned int*)g,
        (__attribute__((address_space(3))) unsigned int*)l, 16, 0, 0);
}

// ---------------------------------------------------------------- embedding
__global__ __launch_bounds__(256) void embed_kernel(
    const int* __restrict__ ids, const float* __restrict__ W, float* __restrict__ x)
{
    int idx = blockIdx.x * 256 + threadIdx.x;
    int d  = idx & (DM - 1);
    int bt = idx >> 10;
    x[idx] = W[(size_t)ids[bt] * DM + d];
}

// ---------------------------------------------------------------- layernorm (row = 1024)
__global__ __launch_bounds__(256) void ln_kernel(
    const float* __restrict__ x, const float* __restrict__ w,
    const float* __restrict__ b, float* __restrict__ o,
    u16* __restrict__ oh, u16* __restrict__ ol)
{
    int row = blockIdx.x;
    const float4* xr = (const float4*)(x + (size_t)row * DM);
    float4 v = xr[threadIdx.x];
    float s = v.x + v.y + v.z + v.w;
    float q = v.x*v.x + v.y*v.y + v.z*v.z + v.w*v.w;
    #pragma unroll
    for (int off = 32; off > 0; off >>= 1) {
        s += __shfl_down(s, off);
        q += __shfl_down(q, off);
    }
    __shared__ float rs_[4], rq_[4];
    __shared__ float mu_s, inv_s;
    int lane = threadIdx.x & 63, wv = threadIdx.x >> 6;
    if (lane == 0) { rs_[wv] = s; rq_[wv] = q; }
    __syncthreads();
    if (threadIdx.x == 0) {
        float S = rs_[0] + rs_[1] + rs_[2] + rs_[3];
        float Q = rq_[0] + rq_[1] + rq_[2] + rq_[3];
        float mu  = S * (1.0f / DM);
        float var = Q * (1.0f / DM) - mu * mu;
        mu_s = mu; inv_s = rsqrtf(var + 1e-5f);
    }
    __syncthreads();
    float mu = mu_s, inv = inv_s;
    float4 wv4 = ((const float4*)w)[threadIdx.x];
    float4 bv4 = ((const float4*)b)[threadIdx.x];
    float4 r;
    r.x = (v.x - mu) * inv * wv4.x + bv4.x;
    r.y = (v.y - mu) * inv * wv4.y + bv4.y;
    r.z = (v.z - mu) * inv * wv4.z + bv4.z;
    r.w = (v.w - mu) * inv * wv4.w + bv4.w;
    if (o) ((float4*)(o + (size_t)row * DM))[threadIdx.x] = r;
    if (oh) {
        uint2 hh, ll; split4(r, hh, ll);
        ((uint2*)(oh + (size_t)row * DM))[threadIdx.x] = hh;
        ((uint2*)(ol + (size_t)row * DM))[threadIdx.x] = ll;
    }
}

// ---------------------------------------------------------------- causal dwconv(K=4) + silu
__global__ __launch_bounds__(256) void conv_silu_kernel(
    const float* __restrict__ xz, const float* __restrict__ cw,
    const float* __restrict__ cb, float* __restrict__ xc,
    u16* __restrict__ xh, u16* __restrict__ xl)
{
    int idx = blockIdx.x * 256 + threadIdx.x;
    int c  = idx & (DI_ - 1);
    int bt = idx >> 11;
    int t  = bt & (T_ - 1);
    const float* base = xz + (size_t)bt * (2 * DI_) + c;
    float w0 = cw[c*KK+0], w1 = cw[c*KK+1], w2 = cw[c*KK+2], w3 = cw[c*KK+3];
    float acc = cb[c];
    if (t >= 3) acc += base[-3 * 2 * DI_] * w0;
    if (t >= 2) acc += base[-2 * 2 * DI_] * w1;
    if (t >= 1) acc += base[-1 * 2 * DI_] * w2;
    acc += base[0] * w3;
    float v = siluf(acc);
    xc[idx] = v;
    if (xh) { u16 h, l; split1(v, h, l); xh[idx] = h; xl[idx] = l; }
}

// ---------------------------------------------------------------- selective scan (2-phase, shfl-free)
__global__ __launch_bounds__(256) void scan_kernel(
    const float* __restrict__ dt, int dt_stride,
    const float* __restrict__ u,
    const float* __restrict__ proj,
    const float* __restrict__ z, int z_stride,
    const float* __restrict__ A_log, const float* __restrict__ Dp,
    float* __restrict__ yf, u16* __restrict__ yh, u16* __restrict__ yl)
{
    int b   = blockIdx.x / (DI_ / 16);
    int di0 = (blockIdx.x % (DI_ / 16)) * 16;
    int tid = threadIdx.x;
    int ci = tid >> 4, n = tid & 15;
    int li = tid >> 4, lc = tid & 15;
    int di = di0 + ci;
    float Av = -__expf(A_log[di * NS + n]);
    float Dv = Dp[di];

    __shared__ float dt_s[16][16], u_s[16][16], Bs[16][16], Cs[16][16];
    __shared__ float ps[16][16][17];

    size_t bt0 = (size_t)b * T_ + li;
    float r_dt = dt[bt0 * dt_stride + di0 + lc];
    float r_u  = u[bt0 * DI_ + di0 + lc];
    float r_B  = proj[bt0 * (RR + 2*NS) + RR + lc];
    float r_C  = proj[bt0 * (RR + 2*NS) + RR + NS + lc];
    float r_z  = z[bt0 * z_stride + di0 + lc];

    float h = 0.0f;
    for (int t0 = 0; t0 < T_; t0 += 16) {
        dt_s[li][lc] = r_dt; u_s[li][lc] = r_u; Bs[li][lc] = r_B; Cs[li][lc] = r_C;
        float cz = r_z;
        if (t0 + 16 < T_) {
            size_t bt2 = (size_t)b * T_ + t0 + 16 + li;
            r_dt = dt[bt2 * dt_stride + di0 + lc];
            r_u  = u[bt2 * DI_ + di0 + lc];
            r_B  = proj[bt2 * (RR + 2*NS) + RR + lc];
            r_C  = proj[bt2 * (RR + 2*NS) + RR + NS + lc];
            r_z  = z[bt2 * z_stride + di0 + lc];
        }
        __syncthreads();
        #pragma unroll
        for (int i = 0; i < 16; i++) {
            float dtv = dt_s[i][ci];
            float uv  = u_s[i][ci];
            float dA  = __expf(dtv * Av);
            h = dA * h + dtv * uv * Bs[i][n];
            float p = h * Cs[i][n];
            if (n == 0) p += uv * Dv;
            ps[i][ci][n] = p;
        }
        __syncthreads();
        float s = 0.0f;
        #pragma unroll
        for (int k = 0; k < 16; k++) s += ps[li][lc][k];
        size_t bty = (size_t)b * T_ + t0 + li;
        float yv = s * siluf(cz);
        size_t oidx = bty * DI_ + di0 + lc;
        if (yf) yf[oidx] = yv;
        if (yh) { u16 hv, lv; split1(yv, hv, lv); yh[oidx] = hv; yl[oidx] = lv; }
    }
}

// ---------------------------------------------------------------- weight conversion
__global__ __launch_bounds__(256) void split_kernel(
    const float* __restrict__ src, u16* __restrict__ hi, u16* __restrict__ lo, int n4)
{
    int i = blockIdx.x * 256 + threadIdx.x;
    int stride = gridDim.x * 256;
    for (; i < n4; i += stride) {
        float4 v = ((const float4*)src)[i];
        uint2 hh, ll; split4(v, hh, ll);
        ((uint2*)hi)[i] = hh; ((uint2*)lo)[i] = ll;
    }
}

__global__ __launch_bounds__(256) void split_xw_kernel(
    const float* __restrict__ src, u16* __restrict__ hi, u16* __restrict__ lo)
{
    int idx = blockIdx.x * 256 + threadIdx.x;
    int l = idx >> 18;
    int rem = idx & 262143;
    int r = rem >> 11, cc = rem & 2047;
    float v = (r < 96) ? src[((size_t)l * 96 + r) * DI_ + cc] : 0.0f;
    u16 h, lo_; split1(v, h, lo_);
    hi[idx] = h; lo[idx] = lo_;
}

__global__ __launch_bounds__(256) void reduce_xproj(
    const float* __restrict__ part, float* __restrict__ proj,
    u16* __restrict__ ph, u16* __restrict__ pl)
{
    int idx = blockIdx.x * 256 + threadIdx.x;
    float s = 0.0f;
    #pragma unroll
    for (int k = 0; k < 8; k++) s += part[(size_t)k * BT * 96 + idx];
    proj[idx] = s;
    u16 h, l; split1(s, h, l); ph[idx] = h; pl[idx] = l;
}

// ---------------------------------------------------------------- bf16x3 MFMA NT GEMM
// Pipelined: double-buffered 4-plane LDS; next K-tile's global_load_lds issued
// before computing current tile; counted s_waitcnt vmcnt(8) + RAW s_barrier
// (never __syncthreads -> no compiler vmcnt(0) drain; loads fly across barriers).
// EPI bits: 1=bias, 2=softplus, 4=residual. SPLITK: blockIdx.x = k-slice. SWZ: XCD remap.
template<int EPI, bool SPLITK, bool SWZ>
__global__ __launch_bounds__(256) void gemm_bf3(
    const u16* __restrict__ Ah, const u16* __restrict__ Al, int lda,
    const u16* __restrict__ Bh, const u16* __restrict__ Bl, int ldb,
    float* __restrict__ C, int ldc,
    const float* __restrict__ bias,
    const float* __restrict__ Res, int ldres,
    int N, int Kd)
{
    __shared__ __align__(16) u16 lds[2][4][128][32];   // 2 buf x {Ah,Al,Bh,Bl} x tile

    int bx = blockIdx.x, by = blockIdx.y;
    if (SWZ) {   // bijective XCD-contiguous remap (grid count % 8 == 0 at call sites)
        int gx = gridDim.x;
        int nwg = gx * gridDim.y;
        int lid = by * gx + bx;
        int s = (lid & 7) * (nwg >> 3) + (lid >> 3);
        bx = s % gx; by = s / gx;
    }

    const int tid  = threadIdx.x;
    const int lane = tid & 63, wave = tid >> 6;
    const int m0 = by * 128;
    int n0, kbeg, kend;
    float* Cb = C;
    if (SPLITK) {
        n0 = 0;
        int KS = Kd >> 3;
        kbeg = bx * KS; kend = kbeg + KS;
        Cb = C + (size_t)bx * BT * 96;
    } else {
        n0 = bx * 128; kbeg = 0; kend = Kd;
    }

    const int lr = lane & 15, lc = lane >> 4;
    const int rsw = (lr >> 1) & 3;
    const int wm = (wave >> 1) * 64, wn = (wave & 1) * 64;

    f32x4 acc[4][4];
    #pragma unroll
    for (int i = 0; i < 4; i++)
        #pragma unroll
        for (int j = 0; j < 4; j++)
            acc[i][j] = (f32x4){0.f, 0.f, 0.f, 0.f};

    // per-wave staging: wave w stages plane w; source chunk pre-swizzled (r3-verified)
    const u16* mat = (wave == 0) ? Ah : (wave == 1) ? Al : (wave == 2) ? Bh : Bl;
    const size_t ldby = ((wave < 2) ? (size_t)lda : (size_t)ldb) * 2;
    const int r0 = (wave < 2) ? m0 : n0;
    const char* gsrc = (const char*)mat + (size_t)(r0 + (lane >> 2)) * ldby
                     + ((((lane & 3) ^ ((lane >> 3) & 3))) << 4);

    // prologue: stage tile 0 into buf 0
    {
        const char* g = gsrc + (size_t)kbeg * 2;
        #pragma unroll
        for (int c = 0; c < 8; c++)
            gload16(g + (size_t)c * 16 * ldby, (void*)&lds[0][wave][c * 16][0]);
    }

    int cur = 0;
    for (int k0 = kbeg; k0 < kend; k0 += 32) {
        const bool pf = (k0 + 32 < kend);
        if (pf) {   // issue next tile's 8 loads into the other buffer
            const char* g = gsrc + (size_t)(k0 + 32) * 2;
            #pragma unroll
            for (int c = 0; c < 8; c++)
                gload16(g + (size_t)c * 16 * ldby, (void*)&lds[cur ^ 1][wave][c * 16][0]);
        }
        __builtin_amdgcn_sched_barrier(0);
        // wait only for MY current-tile loads; next tile's 8 stay in flight
        if (pf) asm volatile("s_waitcnt vmcnt(8)" ::: "memory");
        else    asm volatile("s_waitcnt vmcnt(0)" ::: "memory");
        __builtin_amdgcn_s_barrier();              // all waves' planes staged
        __builtin_amdgcn_sched_barrier(0);         // no ds_read hoists above barrier

        const int cs = (lc ^ rsw) * 8;
        bfrag afh[4], bfh[4];
        #pragma unroll
        for (int i = 0; i < 4; i++) {
            afh[i] = *(const bfrag*)&lds[cur][0][wm + i*16 + lr][cs];
            bfh[i] = *(const bfrag*)&lds[cur][2][wn + i*16 + lr][cs];
        }
        #pragma unroll
        for (int i = 0; i < 4; i++)
            #pragma unroll
            for (int j = 0; j < 4; j++)
                acc[i][j] = __builtin_amdgcn_mfma_f32_16x16x32_bf16(afh[i], bfh[j], acc[i][j], 0, 0, 0);
        bfrag afl[4];
        #pragma unroll
        for (int i = 0; i < 4; i++)
            afl[i] = *(const bfrag*)&lds[cur][1][wm + i*16 + lr][cs];
        #pragma unroll
        for (int i = 0; i < 4; i++)
            #pragma unroll
            for (int j = 0; j < 4; j++)
                acc[i][j] = __builtin_amdgcn_mfma_f32_16x16x32_bf16(afl[i], bfh[j], acc[i][j], 0, 0, 0);
        bfrag bfl[4];
        #pragma unroll
        for (int i = 0; i < 4; i++)
            bfl[i] = *(const bfrag*)&lds[cur][3][wn + i*16 + lr][cs];
        #pragma unroll
        for (int i = 0; i < 4; i++)
            #pragma unroll
            for (int j = 0; j < 4; j++)
                acc[i][j] = __builtin_amdgcn_mfma_f32_16x16x32_bf16(afh[i], bfl[j], acc[i][j], 0, 0, 0);

        asm volatile("s_waitcnt lgkmcnt(0)" ::: "memory");   // my reads retired
        __builtin_amdgcn_s_barrier();              // everyone done reading buf[cur]
        __builtin_amdgcn_sched_barrier(0);
        cur ^= 1;
    }

    // epilogue: D col = lane&15, row = (lane>>4)*4 + reg (m89-verified, r2/r3-passed)
    #pragma unroll
    for (int j = 0; j < 4; j++) {
        int nn = n0 + wn + j*16 + lr;
        if (nn < N) {
            float bs = (EPI & 1) ? bias[nn] : 0.f;
            #pragma unroll
            for (int i = 0; i < 4; i++) {
                #pragma unroll
                for (int r = 0; r < 4; r++) {
                    int m = m0 + wm + i*16 + lc*4 + r;
                    float v = acc[i][j][r];
                    if (EPI & 1) v += bs;
                    if (EPI & 2) v = softplusf(v);
                    if (EPI & 4) v += Res[(size_t)m * ldres + nn];
                    Cb[(size_t)m * ldc + nn] = v;
                }
            }
        }
    }
}

// ---------------------------------------------------------------- round-2 GEMM (ws-size fallback)
template<int EPI, bool NG>
__global__ __launch_bounds__(256) void gemm_nt_mfma(
    const float* __restrict__ A, int lda,
    const float* __restrict__ Bm, int ldb,
    float* __restrict__ C, int ldc,
    const float* __restrict__ bias,
    const float* __restrict__ Res, int ldres,
    int N, int Kd)
{
    __shared__ __align__(16) u16 lds[4][128][40];
    const int tid  = threadIdx.x;
    const int m0   = blockIdx.y * 128, n0 = blockIdx.x * 128;
    const int lane = tid & 63, wave = tid >> 6;
    const int wm   = (wave >> 1) * 64, wn = (wave & 1) * 64;
    const int lr   = lane & 15, lc = lane >> 4;
    f32x4 acc[4][4];
    #pragma unroll
    for (int i = 0; i < 4; i++)
        #pragma unroll
        for (int j = 0; j < 4; j++)
            acc[i][j] = (f32x4){0.f, 0.f, 0.f, 0.f};
    const float* Ab = A  + (size_t)m0 * lda;
    const float* Bb = Bm + (size_t)n0 * ldb;
    for (int k0 = 0; k0 < Kd; k0 += 32) {
        uint2 ahh[4], alo[4], bhh[4], blo[4];
        #pragma unroll
        for (int i = 0; i < 4; i++) {
            int idx = tid + i * 256;
            int r = idx >> 3, c = (idx & 7) << 2;
            float4 av = *(const float4*)(Ab + (size_t)r * lda + k0 + c);
            float4 bv;
            if (!NG || (n0 + r) < N)
                bv = *(const float4*)(Bb + (size_t)r * ldb + k0 + c);
            else
                bv = make_float4(0.f,0.f,0.f,0.f);
            split4(av, ahh[i], alo[i]);
            split4(bv, bhh[i], blo[i]);
        }
        __syncthreads();
        #pragma unroll
        for (int i = 0; i < 4; i++) {
            int idx = tid + i * 256;
            int r = idx >> 3, c = (idx & 7) << 2;
            *(uint2*)&lds[0][r][c] = ahh[i];
            *(uint2*)&lds[1][r][c] = alo[i];
            *(uint2*)&lds[2][r][c] = bhh[i];
            *(uint2*)&lds[3][r][c] = blo[i];
        }
        __syncthreads();
        bfrag afh[4], afl[4], bfh[4], bfl[4];
        #pragma unroll
        for (int i = 0; i < 4; i++) {
            afh[i] = *(const bfrag*)&lds[0][wm + i*16 + lr][lc*8];
            afl[i] = *(const bfrag*)&lds[1][wm + i*16 + lr][lc*8];
            bfh[i] = *(const bfrag*)&lds[2][wn + i*16 + lr][lc*8];
            bfl[i] = *(const bfrag*)&lds[3][wn + i*16 + lr][lc*8];
        }
        #pragma unroll
        for (int i = 0; i < 4; i++)
            #pragma unroll
            for (int j = 0; j < 4; j++) {
                f32x4 a = acc[i][j];
                a = __builtin_amdgcn_mfma_f32_16x16x32_bf16(afh[i], bfh[j], a, 0, 0, 0);
                a = __builtin_amdgcn_mfma_f32_16x16x32_bf16(afl[i], bfh[j], a, 0, 0, 0);
                a = __builtin_amdgcn_mfma_f32_16x16x32_bf16(afh[i], bfl[j], a, 0, 0, 0);
                acc[i][j] = a;
            }
    }
    #pragma unroll
    for (int j = 0; j < 4; j++) {
        int n = n0 + wn + j*16 + lr;
        if (NG && n >= N) continue;
        float bs = (EPI & 1) ? bias[n] : 0.f;
        #pragma unroll
        for (int i = 0; i < 4; i++) {
            #pragma unroll
            for (int r = 0; r < 4; r++) {
                int m = m0 + wm + i*16 + lc*4 + r;
                float v = acc[i][j][r];
                if (EPI & 1) v += bs;
                if (EPI & 2) v = softplusf(v);
                if (EPI & 4) v += Res[(size_t)m * ldres + n];
                C[(size_t)m * ldc + n] = v;
            }
        }
    }
}

// ---------------------------------------------------------------- launch
extern "C" void kernel_launch(void* const* d_in, const int* in_sizes, int n_in,
                              void* d_out, int out_size, void* d_ws, size_t ws_size,
                              hipStream_t stream)
{
    const int*   ids    = (const int*)  d_in[0];
    const float* embedW = (const float*)d_in[1];
    const float* out_b  = (const float*)d_in[2];
    const float* ln_w   = (const float*)d_in[3];
    const float* ln_b   = (const float*)d_in[4];
    const float* norm_w = (const float*)d_in[5];
    const float* norm_b = (const float*)d_in[6];
    const float* inW    = (const float*)d_in[7];
    const float* convW  = (const float*)d_in[8];
    const float* convB  = (const float*)d_in[9];
    const float* xW     = (const float*)d_in[10];
    const float* dtW    = (const float*)d_in[11];
    const float* dtB    = (const float*)d_in[12];
    const float* Alog   = (const float*)d_in[13];
    const float* Dp     = (const float*)d_in[14];
    const float* oW     = (const float*)d_in[15];
    float* logits = (float*)d_out;

    const size_t fX  = (size_t)BT * DM;
    const size_t fXZ = (size_t)BT * 2 * DI_;
    const size_t fXC = (size_t)BT * DI_;
    const size_t fPJ = (size_t)BT * 96;
    float* x    = (float*)d_ws;
    float* xz   = x    + fX;
    float* xc   = xz   + fXZ;
    float* proj = xc   + fXC;
    float* part = proj + fPJ;
    u16* p16 = (u16*)(part + 8 * fPJ);
    u16* hh  = p16; p16 += fX;   u16* hl  = p16; p16 += fX;
    u16* xch = p16; p16 += fXC;  u16* xcl = p16; p16 += fXC;
    u16* pjh = p16; p16 += fPJ;  u16* pjl = p16; p16 += fPJ;
    const size_t winW = (size_t)LL * 2 * DI_ * DM;
    u16* inWh = p16; p16 += winW; u16* inWl = p16; p16 += winW;
    const size_t wxW = (size_t)LL * 128 * DI_;
    u16* xWh = p16; p16 += wxW;  u16* xWl = p16; p16 += wxW;
    const size_t wdtW = (size_t)LL * DI_ * RR;
    u16* dtWh = p16; p16 += wdtW; u16* dtWl = p16; p16 += wdtW;
    const size_t woW = (size_t)LL * DM * DI_;
    u16* oWh = p16; p16 += woW;  u16* oWl = p16; p16 += woW;
    const size_t weW = (size_t)V_ * DM;
    u16* eWh = p16; p16 += weW;  u16* eWl = p16; p16 += weW;
    const size_t NEED = (size_t)((char*)p16 - (char*)d_ws);

    if (ws_size < NEED) {
        // fallback: round-2 pipeline (verified 5186 us)
        float* fx    = (float*)d_ws;
        float* fh    = fx + fX;
        float* fxz   = fh + fX;
        float* fxc   = fxz + fXZ;
        float* fproj = fxc + fXC;
        embed_kernel<<<BT*DM/256, 256, 0, stream>>>(ids, embedW, fx);
        for (int l = 0; l < LL; l++) {
            ln_kernel<<<BT, 256, 0, stream>>>(fx, norm_w + (size_t)l*DM, norm_b + (size_t)l*DM, fh, nullptr, nullptr);
            gemm_nt_mfma<0, false><<<dim3(32, 32), 256, 0, stream>>>(
                fh, DM, inW + (size_t)l*2*DI_*DM, DM, fxz, 2*DI_, nullptr, nullptr, 0, 2*DI_, DM);
            conv_silu_kernel<<<BT*DI_/256, 256, 0, stream>>>(
                fxz, convW + (size_t)l*DI_*KK, convB + (size_t)l*DI_, fxc, nullptr, nullptr);
            gemm_nt_mfma<0, true><<<dim3(1, 32), 256, 0, stream>>>(
                fxc, DI_, xW + (size_t)l*(RR+2*NS)*DI_, DI_, fproj, RR+2*NS, nullptr, nullptr, 0, RR+2*NS, DI_);
            gemm_nt_mfma<3, false><<<dim3(16, 32), 256, 0, stream>>>(
                fproj, RR+2*NS, dtW + (size_t)l*DI_*RR, RR, fxz, 2*DI_, dtB + (size_t)l*DI_, nullptr, 0, DI_, RR);
            scan_kernel<<<B_*(DI_/16), 256, 0, stream>>>(
                fxz, 2*DI_, fxc, fproj, fxz + DI_, 2*DI_,
                Alog + (size_t)l*DI_*NS, Dp + (size_t)l*DI_, fxc, nullptr, nullptr);
            gemm_nt_mfma<4, false><<<dim3(8, 32), 256, 0, stream>>>(
                fxc, DI_, oW + (size_t)l*DM*DI_, DI_, fx, DM, nullptr, fx, DM, DM, DI_);
        }
        ln_kernel<<<BT, 256, 0, stream>>>(fx, ln_w, ln_b, fh, nullptr, nullptr);
        gemm_nt_mfma<1, false><<<dim3(V_/128, 32), 256, 0, stream>>>(
            fh, DM, embedW, DM, logits, V_, out_b, nullptr, 0, V_, DM);
        return;
    }

    split_kernel<<<4096, 256, 0, stream>>>(inW, inWh, inWl, (int)(winW / 4));
    split_kernel<<<2048, 256, 0, stream>>>(dtW, dtWh, dtWl, (int)(wdtW / 4));
    split_kernel<<<4096, 256, 0, stream>>>(oW, oWh, oWl, (int)(woW / 4));
    split_kernel<<<8192, 256, 0, stream>>>(embedW, eWh, eWl, (int)(weW / 4));
    split_xw_kernel<<<4096, 256, 0, stream>>>(xW, xWh, xWl);

    embed_kernel<<<BT*DM/256, 256, 0, stream>>>(ids, embedW, x);

    for (int l = 0; l < LL; l++) {
        ln_kernel<<<BT, 256, 0, stream>>>(x, norm_w + (size_t)l*DM, norm_b + (size_t)l*DM,
                                          nullptr, hh, hl);
        // xz = h @ inW^T   (M=4096, N=4096, K=1024)
        gemm_bf3<0, false, false><<<dim3(32, 32), 256, 0, stream>>>(
            hh, hl, DM, inWh + l*2*DI_*DM, inWl + l*2*DI_*DM, DM,
            xz, 2*DI_, nullptr, nullptr, 0, 2*DI_, DM);
        conv_silu_kernel<<<BT*DI_/256, 256, 0, stream>>>(
            xz, convW + (size_t)l*DI_*KK, convB + (size_t)l*DI_, xc, xch, xcl);
        // x_proj split-K x8 (N=96 padded to 128)
        gemm_bf3<0, true, false><<<dim3(8, 32), 256, 0, stream>>>(
            xch, xcl, DI_, xWh + l*128*DI_, xWl + l*128*DI_, DI_,
            part, 96, nullptr, nullptr, 0, 96, DI_);
        reduce_xproj<<<BT*96/256, 256, 0, stream>>>(part, proj, pjh, pjl);
        // dt = softplus(proj[:, :R] @ dtW^T + dtB) -> x_in slots of xz
        gemm_bf3<3, false, false><<<dim3(16, 32), 256, 0, stream>>>(
            pjh, pjl, 96, dtWh + l*DI_*RR, dtWl + l*DI_*RR, RR,
            xz, 2*DI_, dtB + (size_t)l*DI_, nullptr, 0, DI_, RR);
        scan_kernel<<<B_*(DI_/16), 256, 0, stream>>>(
            xz, 2*DI_, xc, proj, xz + DI_, 2*DI_,
            Alog + (size_t)l*DI_*NS, Dp + (size_t)l*DI_, nullptr, xch, xcl);
        // x += y @ oW^T
        gemm_bf3<4, false, false><<<dim3(8, 32), 256, 0, stream>>>(
            xch, xcl, DI_, oWh + l*DM*DI_, oWl + l*DM*DI_, DI_,
            x, DM, nullptr, x, DM, DM, DI_);
    }

    ln_kernel<<<BT, 256, 0, stream>>>(x, ln_w, ln_b, nullptr, hh, hl);
    // logits = h @ embedW^T + out_b  (M=4096, N=32000, K=1024) — XCD-swizzled
    gemm_bf3<1, false, true><<<dim3(V_/128, 32), 256, 0, stream>>>(
        hh, hl, DM, eWh, eWl, DM, logits, V_, out_b, nullptr, 0, V_, DM);
}